// Round 12
// baseline (463.645 us; speedup 1.0000x reference)
//
#include <hip/hip_runtime.h>
#include <hip/hip_bf16.h>

// C[M,N] = A[M,K] @ W[N,K]^T ; M=32768, N=K=2048. fp32 in/out.
// R12: R7 skeleton (best GEMM, 262us) + A-convert FUSED into staging.
// A staged by reg-path: per K-tile 4 row-block chunks x {2 float4 fp32 loads
// (pre-swizzled source cols) -> 8 cvt -> ds_write_b128 to LINEAR dest} ==
// bit-identical LDS image to R7's gload_lds-from-bf16-ws; read side untouched.
// W still gload_lds from pre-converted ws (W-cvt kernel stays, ~4us).
// Saves the 64us A-convert dispatch; GEMM reads A fp32 (+134MB, absorbed at
// 22% HBM). vmcnt ledger per tile (issue order rb0,rb1,W4 | rb2@g1 | rb3@g2):
//   g1 vmcnt(6): retire rb0 (keep rb1,W4)   g2 vmcnt(6): retire rb1 (keep W4,rb2)
//   g3 vmcnt(2): retire W4,rb2 (keep rb3)   g4 vmcnt(0): retire rb3
// All gates wait on loads aged >=400cyc. Boundary adds lgkmcnt(0) (ds_writes
// must be visible across raw s_barrier).

typedef __attribute__((ext_vector_type(8))) short bf16x8;
typedef __attribute__((ext_vector_type(4))) float f32x4;

#define M_DIM 32768
#define N_DIM 2048
#define K_DIM 2048
#define BM 256
#define BN 256
#define BK 64
#define NT (K_DIM / BK)              // 32
#define NBN (N_DIM / BN)             // 8
#define NWG ((M_DIM / BM) * NBN)     // 1024

typedef __attribute__((address_space(3))) char lds_char;
typedef __attribute__((address_space(1))) char glb_char;

__device__ __forceinline__ unsigned short f2bf(float f) {
    __bf16 b = (__bf16)f;   // RNE
    return __builtin_bit_cast(unsigned short, b);
}

// ---------------- fp32 -> bf16 convert (for W only, 17MB, ~4us) -------------
__global__ __launch_bounds__(256)
void cvt_f32_bf16(const float* __restrict__ src, ushort* __restrict__ dst, int n8) {
    const float4* s4 = (const float4*)src;
    int idx = blockIdx.x * blockDim.x + threadIdx.x;
    int stride = gridDim.x * blockDim.x;
    for (int i = idx; i < n8; i += stride) {
        float4 a = s4[2 * (size_t)i];
        float4 b = s4[2 * (size_t)i + 1];
        ushort r[8] = {f2bf(a.x), f2bf(a.y), f2bf(a.z), f2bf(a.w),
                       f2bf(b.x), f2bf(b.y), f2bf(b.z), f2bf(b.w)};
        *reinterpret_cast<uint4*>(dst + 8 * (size_t)i) =
            *reinterpret_cast<const uint4*>(r);
    }
}

// ---------------- 256^2 8-wave GEMM, fused A-convert ------------------------
__global__ __launch_bounds__(512, 2)
void agmm_fuseA(const float* __restrict__ A, const ushort* __restrict__ W,
                float* __restrict__ C) {
    // sA[buf]: buf*32768 ; sB[buf]: 65536 + buf*32768 (256r x 64c bf16, 128B rows)
    __shared__ __attribute__((aligned(16))) char sm[131072];

    const int tid  = threadIdx.x;
    const int lane = tid & 63;
    const int w    = tid >> 6;      // 0..7
    const int wm   = w >> 2;        // 0..1 -> 128-row half of A tile
    const int wn   = w & 3;         // 0..3 -> 64-col slice of B tile

    const int bid = blockIdx.x;
    const int swz = (bid & 7) * (NWG / 8) + (bid >> 3);  // bijective (NWG%8==0)
    const int bm  = swz >> 3;            // 0..127
    const int bn  = swz & (NBN - 1);     // 0..7

    // staging source pre-swizzle (linear LDS dest; read applies same XOR)
    const int lsub = lane >> 3;                       // row&7 at dest
    const int scol = ((lane & 7) ^ lsub) << 3;        // pre-swizzled col elems

    const float*  Af    = A + (size_t)bm * BM * K_DIM + scol;   // fp32 A
    const ushort* Wbase = W + (size_t)bn * BN * K_DIM + scol;   // bf16 W (ws)

    const int lrow = lane & 15;
    const int fxor = (lrow & 7) << 4;
    const int kcb0 = (lane >> 4) << 4;    // 0,16,32,48 byte k-offset
    const int offk0 = (0 + kcb0) ^ fxor;
    const int offk1 = (64 + kcb0) ^ fxor;

    const int abC = (wm * 128 + lrow) * 128;           // A row base (buf0)
    const int bbC = 65536 + (wn * 64 + lrow) * 128;    // B row base (buf0)

    // this wave's 4 A row-blocks (8 rows each)
    const int r0 = (w << 4), r1 = r0 + 8, r2 = 128 + r0, r3 = 128 + r0 + 8;

    f32x4 acc[8][4];
#pragma unroll
    for (int m = 0; m < 8; ++m)
#pragma unroll
        for (int n = 0; n < 4; ++n)
            acc[m][n] = (f32x4){0.f, 0.f, 0.f, 0.f};
    bf16x8 afA[2][2], afB[2][2];   // double-banked A frags
    bf16x8 bfr[4][2];              // B frags

#define GLD16(SRC, LOFF)                                                       \
    __builtin_amdgcn_global_load_lds((const glb_char*)(SRC),                   \
                                     (lds_char*)(sm + (LOFF)), 16, 0, 0)
    // W staging: 4 gload_lds/wave (rows 16w..16w+15 of both 128-row halves)
#define STAGE_W(KT, BUF) do {                                                  \
        const int rb_ = (w << 4);                                              \
        GLD16(Wbase + (size_t)(rb_ + lsub) * K_DIM + (KT) * BK,                \
              65536 + (BUF) * 32768 + rb_ * 128);                              \
        GLD16(Wbase + (size_t)(rb_ + 8 + lsub) * K_DIM + (KT) * BK,            \
              65536 + (BUF) * 32768 + (rb_ + 8) * 128);                        \
        GLD16(Wbase + (size_t)(128 + rb_ + lsub) * K_DIM + (KT) * BK,          \
              65536 + (BUF) * 32768 + (128 + rb_) * 128);                      \
        GLD16(Wbase + (size_t)(128 + rb_ + 8 + lsub) * K_DIM + (KT) * BK,      \
              65536 + (BUF) * 32768 + (128 + rb_ + 8) * 128);                  \
    } while (0)

    // A chunk: 2 float4 fp32 loads at pre-swizzled cols (elems scol..scol+7)
#define LDA_RB(RB, KT, D0, D1) do {                                            \
        const float* p_ = Af + (size_t)((RB) + lsub) * K_DIM + (KT) * BK;      \
        D0 = *(const float4*)(p_);                                             \
        D1 = *(const float4*)(p_ + 4);                                         \
    } while (0)
    // convert + write 16B to linear dest (same image as gload_lds staging)
#define CVT_WR(RB, BUF, S0, S1) do {                                           \
        ushort q_[8] = {f2bf(S0.x), f2bf(S0.y), f2bf(S0.z), f2bf(S0.w),        \
                        f2bf(S1.x), f2bf(S1.y), f2bf(S1.z), f2bf(S1.w)};       \
        *(bf16x8*)(sm + (BUF) * 32768 + (RB) * 128 + lane * 16) =              \
            *(const bf16x8*)q_;                                                \
    } while (0)

#define RD_A(MT, ABASE, DST) do {                                              \
        _Pragma("unroll") for (int m2 = 0; m2 < 2; ++m2) {                     \
            DST[m2][0] = *(const bf16x8*)(sm + (ABASE) +                       \
                ((MT) * 32 + m2 * 16) * 128 + offk0);                          \
            DST[m2][1] = *(const bf16x8*)(sm + (ABASE) +                       \
                ((MT) * 32 + m2 * 16) * 128 + offk1);                          \
        }                                                                      \
    } while (0)
#define RD_B(BBASE) do {                                                       \
        _Pragma("unroll") for (int n = 0; n < 4; ++n) {                        \
            bfr[n][0] = *(const bf16x8*)(sm + (BBASE) + (n * 16) * 128 + offk0);\
            bfr[n][1] = *(const bf16x8*)(sm + (BBASE) + (n * 16) * 128 + offk1);\
        }                                                                      \
    } while (0)
#define MFMA_Q(Q, AF) do {                                                     \
        __builtin_amdgcn_s_setprio(1);                                         \
        _Pragma("unroll") for (int m2 = 0; m2 < 2; ++m2)                       \
        _Pragma("unroll") for (int n = 0; n < 4; ++n)                          \
        _Pragma("unroll") for (int kk = 0; kk < 2; ++kk)                       \
            acc[(Q) * 2 + m2][n] = __builtin_amdgcn_mfma_f32_16x16x32_bf16(    \
                AF[m2][kk], bfr[n][kk], acc[(Q) * 2 + m2][n], 0, 0, 0);        \
        __builtin_amdgcn_s_setprio(0);                                         \
    } while (0)

#define VMW(N)  asm volatile("s_waitcnt vmcnt(" #N ")" ::: "memory")
#define BOUNDARY do {                                                          \
        asm volatile("s_waitcnt lgkmcnt(0)" ::: "memory");                     \
        __builtin_amdgcn_s_barrier();                                          \
        __builtin_amdgcn_sched_barrier(0);                                     \
    } while (0)

    float4 a0, a1, b0, b1;

    // ---- prologue: stage tile 0 into buf0 (queue: rb0,rb1,W4 | rb2 | rb3)
    LDA_RB(r0, 0, a0, a1);
    LDA_RB(r1, 0, b0, b1);
    STAGE_W(0, 0);
    VMW(6);  CVT_WR(r0, 0, a0, a1);  LDA_RB(r2, 0, a0, a1);
    VMW(6);  CVT_WR(r1, 0, b0, b1);  LDA_RB(r3, 0, b0, b1);
    VMW(2);  CVT_WR(r2, 0, a0, a1);
    VMW(0);  CVT_WR(r3, 0, b0, b1);
    BOUNDARY;

    for (int t = 0; t < NT - 1; ++t) {
        const int cur   = t & 1;
        const int nxt   = cur ^ 1;
        const int abase = cur * 32768 + abC;
        const int bbase = cur * 32768 + bbC;
        // issue next-tile loads (queue: rb0, rb1, W4)
        LDA_RB(r0, t + 1, a0, a1);
        LDA_RB(r1, t + 1, b0, b1);
        STAGE_W(t + 1, nxt);
        // compute current tile, interleaved with chunked convert/write
        RD_B(bbase);
        RD_A(0, abase, afA);
        RD_A(1, abase, afB);
        MFMA_Q(0, afA);
        RD_A(2, abase, afA);
        VMW(6);  CVT_WR(r0, nxt, a0, a1);  LDA_RB(r2, t + 1, a0, a1);
        MFMA_Q(1, afB);
        RD_A(3, abase, afB);
        VMW(6);  CVT_WR(r1, nxt, b0, b1);  LDA_RB(r3, t + 1, b0, b1);
        MFMA_Q(2, afA);
        VMW(2);  CVT_WR(r2, nxt, a0, a1);
        MFMA_Q(3, afB);
        VMW(0);  CVT_WR(r3, nxt, b0, b1);
        BOUNDARY;
    }
    {   // last tile (buf parity 1): no staging
        const int abase = 32768 + abC;
        const int bbase = 32768 + bbC;
        RD_B(bbase);
        RD_A(0, abase, afA);
        RD_A(1, abase, afB);
        MFMA_Q(0, afA);
        RD_A(2, abase, afA);
        MFMA_Q(1, afB);
        RD_A(3, abase, afB);
        MFMA_Q(2, afA);
        MFMA_Q(3, afB);
    }
#undef BOUNDARY
#undef VMW
#undef MFMA_Q
#undef RD_B
#undef RD_A
#undef CVT_WR
#undef LDA_RB
#undef STAGE_W
#undef GLD16

    // epilogue: C/D layout col=lane&15, row=(lane>>4)*4+reg (R1-R11 validated)
    const size_t crow = (size_t)(bm * BM + wm * 128 + ((lane >> 4) << 2));
    const int    ccol = bn * BN + wn * 64 + (lane & 15);
    float* Cp = C + crow * N_DIM + ccol;
#pragma unroll
    for (int m = 0; m < 8; ++m)
#pragma unroll
        for (int j = 0; j < 4; ++j) {
            float* cr = Cp + (size_t)(m * 16 + j) * N_DIM;
#pragma unroll
            for (int n = 0; n < 4; ++n)
                cr[n * 16] = acc[m][n][j];
        }
}

// ---------------- fused fp32 fallback (ws too small; R1-validated) ----------
__global__ __launch_bounds__(256, 2)
void agmm_fused(const float* __restrict__ A, const float* __restrict__ W,
                float* __restrict__ C) {
    __shared__ __attribute__((aligned(16))) char sA[128 * 64 * 2];
    __shared__ __attribute__((aligned(16))) char sB[128 * 64 * 2];

    const int tid  = threadIdx.x;
    const int lane = tid & 63;
    const int wid  = tid >> 6;
    const int wm   = wid >> 1;
    const int wn   = wid & 1;

    const int nwg = (M_DIM / 128) * (N_DIM / 128);
    const int bid = blockIdx.x;
    const int swz = (bid & 7) * (nwg / 8) + (bid >> 3);
    const int bm  = swz >> 4;
    const int bn  = swz & 15;

    const int srow = tid >> 4;
    const int scol = (tid & 15) << 2;

    const float* Ap = A + (size_t)(bm * 128 + srow) * K_DIM + scol;
    const float* Wp = W + (size_t)(bn * 128 + srow) * K_DIM + scol;
    const int wbase = (srow * 128 + (scol << 1)) ^ ((srow & 7) << 4);

    const int lrow = lane & 15;
    const int lkb  = (lane >> 4) << 3;
    const int fxor = (lrow & 7) << 4;
    const int arow0 = (wm * 64 + lrow) * 128;
    const int brow0 = (wn * 64 + lrow) * 128;

    f32x4 acc[4][4];
#pragma unroll
    for (int m = 0; m < 4; ++m)
#pragma unroll
        for (int n = 0; n < 4; ++n)
            acc[m][n] = (f32x4){0.f, 0.f, 0.f, 0.f};

    float4 areg[8], breg[8];
#pragma unroll
    for (int p = 0; p < 8; ++p) {
        areg[p] = *reinterpret_cast<const float4*>(Ap + (size_t)p * 16 * K_DIM);
        breg[p] = *reinterpret_cast<const float4*>(Wp + (size_t)p * 16 * K_DIM);
    }

    for (int kt = 0; kt < NT; ++kt) {
        __syncthreads();
#pragma unroll
        for (int p = 0; p < 8; ++p) {
            ushort av[4] = {f2bf(areg[p].x), f2bf(areg[p].y),
                            f2bf(areg[p].z), f2bf(areg[p].w)};
            *reinterpret_cast<ushort4*>(sA + (wbase + p * 2048)) =
                *reinterpret_cast<ushort4*>(av);
            ushort bv[4] = {f2bf(breg[p].x), f2bf(breg[p].y),
                            f2bf(breg[p].z), f2bf(breg[p].w)};
            *reinterpret_cast<ushort4*>(sB + (wbase + p * 2048)) =
                *reinterpret_cast<ushort4*>(bv);
        }
        __syncthreads();

        if (kt + 1 < NT) {
            const float* ap = Ap + (size_t)(kt + 1) * BK;
            const float* wp = Wp + (size_t)(kt + 1) * BK;
#pragma unroll
            for (int p = 0; p < 8; ++p) {
                areg[p] = *reinterpret_cast<const float4*>(ap + (size_t)p * 16 * K_DIM);
                breg[p] = *reinterpret_cast<const float4*>(wp + (size_t)p * 16 * K_DIM);
            }
        }

#pragma unroll
        for (int kk = 0; kk < 2; ++kk) {
            const int kcb = (kk * 32 + lkb) * 2;
            bf16x8 af[4], bfv[4];
#pragma unroll
            for (int m = 0; m < 4; ++m)
                af[m] = *reinterpret_cast<const bf16x8*>(
                    sA + ((arow0 + m * 2048 + kcb) ^ fxor));
#pragma unroll
            for (int n = 0; n < 4; ++n)
                bfv[n] = *reinterpret_cast<const bf16x8*>(
                    sB + ((brow0 + n * 2048 + kcb) ^ fxor));
#pragma unroll
            for (int m = 0; m < 4; ++m)
#pragma unroll
                for (int n = 0; n < 4; ++n)
                    acc[m][n] = __builtin_amdgcn_mfma_f32_16x16x32_bf16(
                        af[m], bfv[n], acc[m][n], 0, 0, 0);
        }
    }

    const size_t crow = (size_t)(bm * 128 + wm * 64 + ((lane >> 4) << 2));
    const int    ccol = bn * 128 + wn * 64 + (lane & 15);
    float* Cp = C + crow * N_DIM + ccol;
#pragma unroll
    for (int m = 0; m < 4; ++m)
#pragma unroll
        for (int j = 0; j < 4; ++j) {
            float* cr = Cp + (size_t)(m * 16 + j) * N_DIM;
#pragma unroll
            for (int n = 0; n < 4; ++n)
                cr[n * 16] = acc[m][n][j];
        }
}

extern "C" void kernel_launch(void* const* d_in, const int* in_sizes, int n_in,
                              void* d_out, int out_size, void* d_ws, size_t ws_size,
                              hipStream_t stream) {
    const float* A  = (const float*)d_in[0];   // [8,4096,2048] fp32
    const float* Wt = (const float*)d_in[1];   // [2048,2048] fp32
    float* C = (float*)d_out;                  // [32768,2048] fp32

    const size_t needW = (size_t)N_DIM * K_DIM * 2;

    if (ws_size >= needW) {
        ushort* Wbf = (ushort*)d_ws;
        cvt_f32_bf16<<<dim3(512), dim3(256), 0, stream>>>(Wt, Wbf, (N_DIM * K_DIM) / 8);
        agmm_fuseA<<<dim3(NWG), dim3(512), 0, stream>>>(A, Wbf, C);
    } else {
        agmm_fused<<<dim3((M_DIM / 128) * (N_DIM / 128)), dim3(256), 0, stream>>>(A, Wt, C);
    }
}